// Round 21
// baseline (262.083 us; speedup 1.0000x reference)
//
#include <hip/hip_runtime.h>
#include <math.h>

typedef _Float16 f16;
typedef _Float16 f16x2 __attribute__((ext_vector_type(2)));
typedef _Float16 f16x4 __attribute__((ext_vector_type(4)));
typedef _Float16 f16x8 __attribute__((ext_vector_type(8)));
typedef float f32x16 __attribute__((ext_vector_type(16)));

// ---------------------------------------------------------------------------
// Protein repack for 32x32x16: conflict-free lane-contiguous B layout.
//   idx = ((t*2+ks)*3 + c3)*512 + lane*8 + e
//   ch = c3*32 + (lane&31); v = ks*16 + (lane>>5)*8 + e  (zero for v >= 25)
// ---------------------------------------------------------------------------
__global__ void repack_pro_kernel(const float* __restrict__ w, f16* __restrict__ wp) {
    constexpr int V = 25, K = 8;
    int i = blockIdx.x * 256 + threadIdx.x;     // [0, 24576)
    if (i >= 24576) return;
    int e = i & 7, l = (i >> 3) & 63, c3 = (i >> 9) % 3, tk = i / (512 * 3);
    int t = tk >> 1, ks = tk & 1;
    int ch = c3 * 32 + (l & 31), v = ks * 16 + (l >> 5) * 8 + e;
    float val = (v < V) ? w[(ch * V + v) * K + t] : 0.f;
    wp[i] = (f16)val;
}

// ---------------------------------------------------------------------------
// Ligand repack for 32x32x16: tk = t*4+ks (V=64 -> 4 ksteps of 16).
// ---------------------------------------------------------------------------
__global__ void repack_lig_kernel(const float* __restrict__ w, f16* __restrict__ wp) {
    constexpr int V = 64, K = 4;
    int i = blockIdx.x * 256 + threadIdx.x;     // [0, 24576)
    if (i >= 24576) return;
    int e = i & 7, l = (i >> 3) & 63, c3 = (i >> 9) % 3, tk = i / (512 * 3);
    int t = tk >> 2, ks = tk & 3;
    int ch = c3 * 32 + (l & 31), v = ks * 16 + (l >> 5) * 8 + e;
    wp[i] = (f16)w[(ch * V + v) * K + t];
}

// ---------------------------------------------------------------------------
// MERGED conv, 32x32x16 MFMA (2x DS arithmetic intensity vs 16x16x32; r20
// counters showed DS-read = top pipe at 60%). 256 thr (4 waves), 2 blocks/CU.
// Wave owns 2 row-tiles of 32 x ALL 96 ch (3 col-tiles): DS reads/chunk-block
// 448 -> 320; MFMA cyc -17% (32x32 rate). acc[2][3] f32x16 = 96 VGPR at
// launch_bounds(256,2) = 256-reg tier (no spill). Staging/chunking = r20.
// Fragments: A row=lane&31, k=(lane>>5)*8+e; C/D col=lane&31,
// row=(i&3)+8*(i>>2)+4*(lane>>5)  [r2-proven].
// ---------------------------------------------------------------------------
__global__ __launch_bounds__(256, 2) void conv_kernel(
    const float* __restrict__ pro,   // (B, 25, 1000) f32
    const f16*   __restrict__ wpP,
    const float* __restrict__ bP,    // (96)
    const float* __restrict__ lig,   // (B, 64, 100) f32
    const f16*   __restrict__ wpL,
    const float* __restrict__ bL,    // (96)
    float* __restrict__ feat,        // (B, 192)
    int B)
{
    __shared__ __align__(16) char s_raw[264 * 80];   // 21.1 KB (lig: 136*144)
    __shared__ __align__(16) f16  s_w[24576];        // 49.15 KB
    __shared__ float s_red[4 * 96];                  // 1.5 KB

    const int tid  = threadIdx.x;
    const int wave = tid >> 6;        // 0..3
    const int lane = tid & 63;
    const int q    = lane >> 5;       // k-half of fragment
    const int r31  = lane & 31;       // A-row / B-col in 32-tile

    if ((int)blockIdx.x < B) {
        // ================= PROTEIN path =================
        constexpr int V = 25, L = 1000, KT = 8, LOUT = 993;
        constexpr int CH = 256, NC = 4, BR = 264, RSB = 80;
        constexpr int P4 = BR / 4;                 // 66
        constexpr int NU = 7 * P4;                 // 462 staging units
        const size_t b = blockIdx.x;
        const float* gs = pro + b * (size_t)(V * L);

        {   const f16x8* wg = (const f16x8*)wpP;
            f16x8* wl = (f16x8*)s_w;
            #pragma unroll
            for (int u = 0; u < 12; ++u)
                wl[u * 256 + tid] = wg[u * 256 + tid];
        }
        for (int row = tid; row < BR; row += 256) {      // zero v-pad bytes 48..63
            const int swz = ((row >> 3) & 3) << 4;
            *(f16x8*)(s_raw + row * RSB + (48 ^ swz)) = (f16x8){};
        }
        __syncthreads();

        float runmax[3];
        #pragma unroll
        for (int c3 = 0; c3 < 3; ++c3) runmax[c3] = -3.0e38f;

        for (int c = 0; c < NC; ++c) {
            if (c) __syncthreads();
            // ---- stage (r20 scheme): vocab-quad units, 4 float4 + 4 b64 ----
            #pragma unroll
            for (int u = 0; u < 2; ++u) {
                const int i = u * 256 + tid;
                if (i < NU) {
                    const int vq = i / P4, p4 = i - vq * P4;
                    const int p = 4 * p4, gp = c * CH + p;
                    float4 x0 = {0.f,0.f,0.f,0.f}, x1 = {0.f,0.f,0.f,0.f};
                    float4 x2 = {0.f,0.f,0.f,0.f}, x3 = {0.f,0.f,0.f,0.f};
                    if (gp < L) {
                        x0 = *(const float4*)(gs + (size_t)(4 * vq) * L + gp);
                        if (vq < 6) {
                            x1 = *(const float4*)(gs + (size_t)(4 * vq + 1) * L + gp);
                            x2 = *(const float4*)(gs + (size_t)(4 * vq + 2) * L + gp);
                            x3 = *(const float4*)(gs + (size_t)(4 * vq + 3) * L + gp);
                        }
                    }
                    const int pb = 8 * vq;
                    const int slot = pb & 48, sub = pb & 8;
                    const float a0[4] = {x0.x, x0.y, x0.z, x0.w};
                    const float a1[4] = {x1.x, x1.y, x1.z, x1.w};
                    const float a2[4] = {x2.x, x2.y, x2.z, x2.w};
                    const float a3[4] = {x3.x, x3.y, x3.z, x3.w};
                    #pragma unroll
                    for (int j = 0; j < 4; ++j) {
                        const int row = p + j;
                        const int swz = ((row >> 3) & 3) << 4;
                        f16x4 hv = { (f16)a0[j], (f16)a1[j], (f16)a2[j], (f16)a3[j] };
                        *(f16x4*)(s_raw + row * RSB + ((slot ^ swz) + sub)) = hv;
                    }
                }
            }
            __syncthreads();

            // ---- compute: wave owns tiles {wave*2, wave*2+1}, all 96 ch ----
            f32x16 acc[2][3] = {};
            #pragma unroll 1
            for (int t = 0; t < KT; ++t) {
                #pragma unroll
                for (int ks = 0; ks < 2; ++ks) {
                    f16x8 bf[3];
                    #pragma unroll
                    for (int c3 = 0; c3 < 3; ++c3)
                        bf[c3] = *(const f16x8*)(s_w + (((t * 2 + ks) * 3 + c3) * 64 + lane) * 8);
                    #pragma unroll
                    for (int tt = 0; tt < 2; ++tt) {
                        const int row = wave * 64 + tt * 32 + r31 + t;   // <= 262
                        const int swz = ((row >> 3) & 3) << 4;
                        f16x8 a = *(const f16x8*)(s_raw + row * RSB + (((ks * 32 + q * 16)) ^ swz));
                        #pragma unroll
                        for (int c3 = 0; c3 < 3; ++c3)
                            acc[tt][c3] = __builtin_amdgcn_mfma_f32_32x32x16_f16(a, bf[c3], acc[tt][c3], 0, 0, 0);
                    }
                }
            }
            // ---- fold; C/D: col=lane&31, row=(i&3)+8*(i>>2)+4*q ----
            #pragma unroll
            for (int tt = 0; tt < 2; ++tt) {
                const int pt = c * CH + wave * 64 + tt * 32;
                if (pt + 32 <= LOUT) {
                    #pragma unroll
                    for (int c3 = 0; c3 < 3; ++c3)
                        #pragma unroll
                        for (int i = 0; i < 16; ++i)
                            runmax[c3] = fmaxf(runmax[c3], acc[tt][c3][i]);
                } else {
                    #pragma unroll
                    for (int c3 = 0; c3 < 3; ++c3)
                        #pragma unroll
                        for (int i = 0; i < 16; ++i) {
                            const int rr = (i & 3) + 8 * (i >> 2) + 4 * q;
                            if (pt + rr < LOUT) runmax[c3] = fmaxf(runmax[c3], acc[tt][c3][i]);
                        }
                }
            }
        }

        // ---- reduce: col c3*32+r31 held by lanes r31 and r31+32 ----
        #pragma unroll
        for (int c3 = 0; c3 < 3; ++c3)
            runmax[c3] = fmaxf(runmax[c3], __shfl_xor(runmax[c3], 32, 64));
        if (lane < 32) {
            #pragma unroll
            for (int c3 = 0; c3 < 3; ++c3)
                s_red[wave * 96 + c3 * 32 + r31] = runmax[c3];
        }
        __syncthreads();
        if (tid < 96) {
            float m = fmaxf(fmaxf(s_red[tid], s_red[96 + tid]),
                            fmaxf(s_red[192 + tid], s_red[288 + tid]));
            feat[b * 192 + 96 + tid] = fmaxf(m + bP[tid], 0.f);
        }
    } else {
        // ================= LIGAND path (32x32, V=64, 4 ksteps) =================
        constexpr int V = 64, L = 100, KT = 4, LOUT = 97;
        constexpr int BR = 136, RSB = 144;         // 19.6 KB < 21.1
        constexpr int P4 = BR / 4;                 // 34
        constexpr int NU = 16 * P4;                // 544 (vocab-quads)
        const size_t b = blockIdx.x - B;
        const float* gs = lig + b * (size_t)(V * L);

        {   const f16x8* wg = (const f16x8*)wpL;
            f16x8* wl = (f16x8*)s_w;
            #pragma unroll
            for (int u = 0; u < 12; ++u)
                wl[u * 256 + tid] = wg[u * 256 + tid];
        }
        // stage whole sample (rows >= L zero-filled; all payload written)
        #pragma unroll
        for (int u = 0; u < 3; ++u) {
            const int i = u * 256 + tid;
            if (i < NU) {
                const int vq = i / P4, p4 = i - vq * P4;
                const int p = 4 * p4;
                float4 x0 = {0.f,0.f,0.f,0.f}, x1 = {0.f,0.f,0.f,0.f};
                float4 x2 = {0.f,0.f,0.f,0.f}, x3 = {0.f,0.f,0.f,0.f};
                if (p < L) {
                    x0 = *(const float4*)(gs + (size_t)(4 * vq) * L + p);
                    x1 = *(const float4*)(gs + (size_t)(4 * vq + 1) * L + p);
                    x2 = *(const float4*)(gs + (size_t)(4 * vq + 2) * L + p);
                    x3 = *(const float4*)(gs + (size_t)(4 * vq + 3) * L + p);
                }
                const int pb = 8 * vq;             // 0..120
                const int slot = pb & 0x70, sub = pb & 8;
                const float a0[4] = {x0.x, x0.y, x0.z, x0.w};
                const float a1[4] = {x1.x, x1.y, x1.z, x1.w};
                const float a2[4] = {x2.x, x2.y, x2.z, x2.w};
                const float a3[4] = {x3.x, x3.y, x3.z, x3.w};
                #pragma unroll
                for (int j = 0; j < 4; ++j) {
                    const int row = p + j;
                    const int swz = ((row >> 3) & 3) << 4;
                    f16x4 hv = { (f16)a0[j], (f16)a1[j], (f16)a2[j], (f16)a3[j] };
                    *(f16x4*)(s_raw + row * RSB + ((slot ^ swz) + sub)) = hv;
                }
            }
        }
        __syncthreads();

        // compute: wave owns row-tile `wave` (rows wave*32..+31), all 96 ch
        f32x16 acc[3] = {};
        #pragma unroll 1
        for (int t = 0; t < KT; ++t) {
            #pragma unroll
            for (int ks = 0; ks < 4; ++ks) {
                f16x8 bf[3];
                #pragma unroll
                for (int c3 = 0; c3 < 3; ++c3)
                    bf[c3] = *(const f16x8*)(s_w + (((t * 4 + ks) * 3 + c3) * 64 + lane) * 8);
                const int row = wave * 32 + r31 + t;           // <= 130 < 136
                const int swz = ((row >> 3) & 3) << 4;
                f16x8 a = *(const f16x8*)(s_raw + row * RSB + (((ks * 32 + q * 16)) ^ swz));
                #pragma unroll
                for (int c3 = 0; c3 < 3; ++c3)
                    acc[c3] = __builtin_amdgcn_mfma_f32_32x32x16_f16(a, bf[c3], acc[c3], 0, 0, 0);
            }
        }
        float runmax[3];
        #pragma unroll
        for (int c3 = 0; c3 < 3; ++c3) {
            runmax[c3] = -3.0e38f;
            #pragma unroll
            for (int i = 0; i < 16; ++i) {
                const int rr = (i & 3) + 8 * (i >> 2) + 4 * q;
                if (wave * 32 + rr < LOUT) runmax[c3] = fmaxf(runmax[c3], acc[c3][i]);
            }
            runmax[c3] = fmaxf(runmax[c3], __shfl_xor(runmax[c3], 32, 64));
        }
        if (lane < 32) {
            #pragma unroll
            for (int c3 = 0; c3 < 3; ++c3)
                s_red[wave * 96 + c3 * 32 + r31] = runmax[c3];
        }
        __syncthreads();
        if (tid < 96) {
            float m = fmaxf(fmaxf(s_red[tid], s_red[96 + tid]),
                            fmaxf(s_red[192 + tid], s_red[288 + tid]));
            feat[b * 192 + tid] = fmaxf(m + bL[tid], 0.f);
        }
    }
}

// ---------------------------------------------------------------------------
// Gram + L2 normalize + readout (4 samples/block, one wave each).
// ---------------------------------------------------------------------------
__global__ __launch_bounds__(256) void gram_affinity_kernel(
    const float* __restrict__ feat, const float* __restrict__ w_aff,
    const float* __restrict__ b_aff, float* __restrict__ out, int B)
{
    const int lane = threadIdx.x & 63;
    const int wid  = threadIdx.x >> 6;
    const int b    = blockIdx.x * 4 + wid;

    __shared__ float s_x[4][192];

    if (b < B) {
        const float* fp = feat + (size_t)b * 192;
        for (int i = lane; i < 192; i += 64) s_x[wid][i] = fp[i];
    }
    __syncthreads();

    if (b < B) {
        float ssum = 0.f, sdot = 0.f;
        #pragma unroll
        for (int t = 0; t < 16; ++t) {
            const int jk = t * 64 + lane;
            const int j = jk >> 5, k = jk & 31;
            float gg = 0.f;
            #pragma unroll
            for (int i = 0; i < 6; ++i)
                gg = fmaf(s_x[wid][i * 32 + j], s_x[wid][i * 32 + k], gg);
            ssum = fmaf(gg, gg, ssum);
            sdot = fmaf(gg, w_aff[jk], sdot);
        }
        #pragma unroll
        for (int off = 32; off >= 1; off >>= 1) {
            ssum += __shfl_xor(ssum, off, 64);
            sdot += __shfl_xor(sdot, off, 64);
        }
        if (lane == 0) out[b] = sdot / (sqrtf(ssum) + 1e-12f) + b_aff[0];
    }
}

extern "C" void kernel_launch(void* const* d_in, const int* in_sizes, int n_in,
                              void* d_out, int out_size, void* d_ws, size_t ws_size,
                              hipStream_t stream)
{
    const float* protein = (const float*)d_in[0];  // (B, 25, 1000)
    const float* ligand  = (const float*)d_in[1];  // (B, 64, 100)
    const float* w_pro   = (const float*)d_in[2];  // (96, 25, 8)
    const float* b_pro   = (const float*)d_in[3];  // (96,)
    const float* w_lig   = (const float*)d_in[4];  // (96, 64, 4)
    const float* b_lig   = (const float*)d_in[5];  // (96,)
    const float* w_aff   = (const float*)d_in[6];  // (1024,)
    const float* b_aff   = (const float*)d_in[7];  // (1,)
    float* out = (float*)d_out;
    const int B = out_size;                        // 4096

    float* feat   = (float*)d_ws;                              // (B,192) f32
    f16*   wpackP = (f16*)((char*)d_ws + (size_t)B * 192 * 4); // 24576 f16
    f16*   wpackL = wpackP + 24576;                            // 24576 f16

    repack_pro_kernel<<<96, 256, 0, stream>>>(w_pro, wpackP);
    repack_lig_kernel<<<96, 256, 0, stream>>>(w_lig, wpackL);

    // merged conv: blocks [0,B) protein -> feat[:,96:], [B,2B) ligand -> feat[:,:96]
    conv_kernel<<<2 * B, 256, 0, stream>>>(
        protein, wpackP, b_pro, ligand, wpackL, b_lig, feat, B);

    gram_affinity_kernel<<<(B + 3) / 4, 256, 0, stream>>>(feat, w_aff, b_aff, out, B);
}

// Round 22
// 245.060 us; speedup vs baseline: 1.0695x; 1.0695x over previous
//
#include <hip/hip_runtime.h>
#include <math.h>

typedef _Float16 f16;
typedef _Float16 f16x2 __attribute__((ext_vector_type(2)));
typedef _Float16 f16x4 __attribute__((ext_vector_type(4)));
typedef _Float16 f16x8 __attribute__((ext_vector_type(8)));
typedef float f32x4 __attribute__((ext_vector_type(4)));

// ---------------------------------------------------------------------------
// Protein repack: CONFLICT-FREE B layout (r14, proven).
// ---------------------------------------------------------------------------
__global__ void repack_pro_kernel(const float* __restrict__ w, f16* __restrict__ wp) {
    constexpr int V = 25, K = 8;
    int i = blockIdx.x * 256 + threadIdx.x;     // [0, 8*6*64*8)
    if (i >= K * 6 * 64 * 8) return;
    int e = i & 7, l = (i >> 3) & 63, c6 = (i >> 9) % 6, t = i / (512 * 6);
    int r16 = l & 15, g = l >> 4;
    int ch = c6 * 16 + r16, v = g * 8 + e;
    float val = (v < V) ? w[(ch * V + v) * K + t] : 0.f;
    wp[i] = (f16)val;
}

// ---------------------------------------------------------------------------
// Ligand repack: conflict-free, tk = t*2+ks (r17, proven).
// ---------------------------------------------------------------------------
__global__ void repack_lig_kernel(const float* __restrict__ w, f16* __restrict__ wp) {
    constexpr int V = 64, K = 4;
    int i = blockIdx.x * 256 + threadIdx.x;     // [0, 8*6*64*8)
    if (i >= 8 * 6 * 64 * 8) return;
    int e = i & 7, l = (i >> 3) & 63, c6 = (i >> 9) % 6, tk = i / (512 * 6);
    int t = tk >> 1, ks = tk & 1;
    int r16 = l & 15, g = l >> 4;
    int ch = c6 * 16 + r16, v = ks * 32 + g * 8 + e;
    wp[i] = (f16)w[(ch * V + v) * K + t];
}

// ---------------------------------------------------------------------------
// MERGED conv (r20 == best measured: conv 239us, total 245us, VGPR 52).
// 512 thr, 2 blocks/CU, CH=256/NC=4, LDS weights, transient-only regs:
//  * (4,2) wave split: rw=wave&3 owns 64 rows, cw=wave>>2 owns 48 ch.
//  * staging unit = vocab-QUAD: 4 coalesced float4 loads + 4 ds_write_b64.
//  * conflict-free [t][c6][lane] B layout; XOR-swizzled A rows.
// Envelope constraints proven over r3-r21: acc <= 48 regs at (512,4);
// no cross-barrier register arrays; no source-level pipelining.
// ---------------------------------------------------------------------------
__global__ __launch_bounds__(512, 4) void conv_kernel(
    const float* __restrict__ pro,   // (B, 25, 1000) f32
    const f16*   __restrict__ wpP,   // protein weights, conflict-free
    const float* __restrict__ bP,    // (96)
    const float* __restrict__ lig,   // (B, 64, 100) f32
    const f16*   __restrict__ wpL,   // ligand weights, conflict-free
    const float* __restrict__ bL,    // (96)
    float* __restrict__ feat,        // (B, 192)
    int B)
{
    __shared__ __align__(16) char s_raw[264 * 80];   // 21.1 KB (lig: 120*144)
    __shared__ __align__(16) f16  s_w[24576];        // 49.15 KB
    __shared__ float s_red[8 * 96];                  // 3 KB

    const int tid  = threadIdx.x;
    const int wave = tid >> 6;        // 0..7
    const int lane = tid & 63;
    const int g    = lane >> 4;       // k-oct
    const int r16  = lane & 15;       // A-row / B-col in 16-tile

    if ((int)blockIdx.x < B) {
        // ================= PROTEIN path =================
        constexpr int V = 25, L = 1000, KT = 8, LOUT = 993;
        constexpr int CH = 256, NC = 4, BR = 264, RSB = 80;
        constexpr int P4 = BR / 4;                 // 66
        constexpr int NU = 7 * P4;                 // 462 staging units (vq 0..6)
        const size_t b = blockIdx.x;
        const float* gs = pro + b * (size_t)(V * L);
        const int rw = wave & 3, cw = wave >> 2;

        {   const f16x8* wg = (const f16x8*)wpP;
            f16x8* wl = (f16x8*)s_w;
            #pragma unroll
            for (int u = 0; u < 24576 / 8 / 512; ++u)    // 6 iters
                wl[u * 512 + tid] = wg[u * 512 + tid];
        }
        for (int row = tid; row < BR; row += 512) {      // zero v-pad slot
            const int swz = ((row >> 3) & 3) << 4;
            *(f16x8*)(s_raw + row * RSB + (48 ^ swz)) = (f16x8){};
        }
        __syncthreads();

        float runmax[3];
        #pragma unroll
        for (int c3 = 0; c3 < 3; ++c3) runmax[c3] = -3.0e38f;

        for (int c = 0; c < NC; ++c) {
            if (c) __syncthreads();
            // ---- stage: unit = (vocab-quad, p-quad); 4x float4 + 4x b64 ----
            if (tid < NU) {
                const int vq = tid / P4, p4 = tid - vq * P4;
                const int p = 4 * p4, gp = c * CH + p;
                float4 x0 = {0.f,0.f,0.f,0.f}, x1 = {0.f,0.f,0.f,0.f};
                float4 x2 = {0.f,0.f,0.f,0.f}, x3 = {0.f,0.f,0.f,0.f};
                if (gp < L) {
                    x0 = *(const float4*)(gs + (size_t)(4 * vq) * L + gp);
                    if (vq < 6) {
                        x1 = *(const float4*)(gs + (size_t)(4 * vq + 1) * L + gp);
                        x2 = *(const float4*)(gs + (size_t)(4 * vq + 2) * L + gp);
                        x3 = *(const float4*)(gs + (size_t)(4 * vq + 3) * L + gp);
                    }
                }
                const int pb = 8 * vq;             // payload byte of v=4vq
                const int slot = pb & 48, sub = pb & 8;
                const float a0[4] = {x0.x, x0.y, x0.z, x0.w};
                const float a1[4] = {x1.x, x1.y, x1.z, x1.w};
                const float a2[4] = {x2.x, x2.y, x2.z, x2.w};
                const float a3[4] = {x3.x, x3.y, x3.z, x3.w};
                #pragma unroll
                for (int j = 0; j < 4; ++j) {
                    const int row = p + j;
                    const int swz = ((row >> 3) & 3) << 4;
                    f16x4 hv = { (f16)a0[j], (f16)a1[j], (f16)a2[j], (f16)a3[j] };
                    *(f16x4*)(s_raw + row * RSB + ((slot ^ swz) + sub)) = hv;
                }
            }
            __syncthreads();

            // ---- compute: rw owns 64 rows (4 tiles), cw owns 48 ch (3 c6) ----
            f32x4 acc[4][3] = {};
            #pragma unroll 1
            for (int t = 0; t < KT; ++t) {
                f16x8 bf[3];
                #pragma unroll
                for (int c3 = 0; c3 < 3; ++c3)
                    bf[c3] = *(const f16x8*)(s_w + ((t * 6 + cw * 3 + c3) * 64 + lane) * 8);
                #pragma unroll
                for (int rt = 0; rt < 4; ++rt) {
                    const int row = rw * 64 + rt * 16 + r16 + t;   // <= 262 < 264
                    const int swz = ((row >> 3) & 3) << 4;
                    f16x8 a = *(const f16x8*)(s_raw + row * RSB + ((g * 16) ^ swz));
                    #pragma unroll
                    for (int c3 = 0; c3 < 3; ++c3)
                        acc[rt][c3] = __builtin_amdgcn_mfma_f32_16x16x32_f16(a, bf[c3], acc[rt][c3], 0, 0, 0);
                }
            }
            // ---- fold; C/D: col=lane&15, row=g*4+i ----
            #pragma unroll
            for (int rt = 0; rt < 4; ++rt) {
                const int pt = c * CH + rw * 64 + rt * 16;
                if (pt + 16 <= LOUT) {
                    #pragma unroll
                    for (int c3 = 0; c3 < 3; ++c3)
                        #pragma unroll
                        for (int i = 0; i < 4; ++i)
                            runmax[c3] = fmaxf(runmax[c3], acc[rt][c3][i]);
                } else {
                    const int p0g = pt + g * 4;
                    #pragma unroll
                    for (int c3 = 0; c3 < 3; ++c3)
                        #pragma unroll
                        for (int i = 0; i < 4; ++i)
                            if (p0g + i < LOUT) runmax[c3] = fmaxf(runmax[c3], acc[rt][c3][i]);
                }
            }
        }

        // ---- reduce: wave = cw*4+rw; each wave owns 48 channels ----
        #pragma unroll
        for (int c3 = 0; c3 < 3; ++c3) {
            runmax[c3] = fmaxf(runmax[c3], __shfl_xor(runmax[c3], 16, 64));
            runmax[c3] = fmaxf(runmax[c3], __shfl_xor(runmax[c3], 32, 64));
        }
        if (lane < 16) {
            #pragma unroll
            for (int c3 = 0; c3 < 3; ++c3)
                s_red[wave * 48 + c3 * 16 + lane] = runmax[c3];
        }
        __syncthreads();
        if (tid < 96) {
            const int cw2 = tid / 48, chs = tid - cw2 * 48;
            float m = s_red[(cw2 * 4) * 48 + chs];
            #pragma unroll
            for (int rw2 = 1; rw2 < 4; ++rw2)
                m = fmaxf(m, s_red[(cw2 * 4 + rw2) * 48 + chs]);
            feat[b * 192 + 96 + tid] = fmaxf(m + bP[tid], 0.f);
        }
    } else {
        // ================= LIGAND path (r17 verbatim) =================
        constexpr int V = 64, L = 100, KT = 4, LOUT = 97;
        constexpr int BR = 120, RSB = 144;
        constexpr int P4 = BR / 4, NU = 32 * P4;   // 960
        const size_t b = blockIdx.x - B;
        const float* gs = lig + b * (size_t)(V * L);

        {   const f16x8* wg = (const f16x8*)wpL;
            f16x8* wl = (f16x8*)s_w;
            #pragma unroll
            for (int u = 0; u < 24576 / 8 / 512; ++u)    // 6 iters
                wl[u * 512 + tid] = wg[u * 512 + tid];
        }
        #pragma unroll
        for (int u = 0; u < 2; ++u) {
            const int i = u * 512 + tid;
            if (i < NU) {
                const int v2 = i / P4, p4 = i - v2 * P4;
                const int p  = 4 * p4;
                float4 x0 = {0.f, 0.f, 0.f, 0.f}, x1 = {0.f, 0.f, 0.f, 0.f};
                if (p < L) {
                    x0 = *(const float4*)(gs + (size_t)(2 * v2) * L + p);
                    x1 = *(const float4*)(gs + (size_t)(2 * v2 + 1) * L + p);
                }
                const int pb = 4 * v2;                    // 0..124
                const int slot = pb & 0x70, sub = pb & 12;
                const float vx0[4] = {x0.x, x0.y, x0.z, x0.w};
                const float vx1[4] = {x1.x, x1.y, x1.z, x1.w};
                #pragma unroll
                for (int j = 0; j < 4; ++j) {
                    const int row = p + j;
                    const int swz = ((row >> 3) & 3) << 4;
                    f16x2 hv = { (f16)vx0[j], (f16)vx1[j] };
                    *(f16x2*)(s_raw + row * RSB + ((slot ^ swz) + sub)) = hv;
                }
            }
        }
        __syncthreads();

        if (wave < 7) {
            f32x4 acc[6] = {};
            #pragma unroll 1
            for (int t = 0; t < KT; ++t) {
                #pragma unroll
                for (int ks = 0; ks < 2; ++ks) {
                    f16x8 bf[6];
                    #pragma unroll
                    for (int c6 = 0; c6 < 6; ++c6)
                        bf[c6] = *(const f16x8*)(s_w + (((t * 2 + ks) * 6 + c6) * 64 + lane) * 8);
                    const int row = wave * 16 + r16 + t;       // <= 114 < 120
                    const int swz = ((row >> 3) & 3) << 4;
                    f16x8 a = *(const f16x8*)(s_raw + row * RSB + ((ks * 64 + g * 16) ^ swz));
                    #pragma unroll
                    for (int c6 = 0; c6 < 6; ++c6)
                        acc[c6] = __builtin_amdgcn_mfma_f32_16x16x32_f16(a, bf[c6], acc[c6], 0, 0, 0);
                }
            }
            float runmax[6];
            const int p0g = wave * 16 + g * 4;
            #pragma unroll
            for (int c6 = 0; c6 < 6; ++c6) {
                runmax[c6] = -3.0e38f;
                #pragma unroll
                for (int i = 0; i < 4; ++i)
                    if (p0g + i < LOUT) runmax[c6] = fmaxf(runmax[c6], acc[c6][i]);
                runmax[c6] = fmaxf(runmax[c6], __shfl_xor(runmax[c6], 16, 64));
                runmax[c6] = fmaxf(runmax[c6], __shfl_xor(runmax[c6], 32, 64));
            }
            if (lane < 16) {
                #pragma unroll
                for (int c6 = 0; c6 < 6; ++c6)
                    s_red[wave * 96 + c6 * 16 + lane] = runmax[c6];
            }
        }
        __syncthreads();
        if (tid < 96) {
            float m = s_red[tid];
            #pragma unroll
            for (int w = 1; w < 7; ++w) m = fmaxf(m, s_red[w * 96 + tid]);
            feat[b * 192 + tid] = fmaxf(m + bL[tid], 0.f);
        }
    }
}

// ---------------------------------------------------------------------------
// Gram + L2 normalize + readout (4 samples/block, one wave each).
// ---------------------------------------------------------------------------
__global__ __launch_bounds__(256) void gram_affinity_kernel(
    const float* __restrict__ feat, const float* __restrict__ w_aff,
    const float* __restrict__ b_aff, float* __restrict__ out, int B)
{
    const int lane = threadIdx.x & 63;
    const int wid  = threadIdx.x >> 6;
    const int b    = blockIdx.x * 4 + wid;

    __shared__ float s_x[4][192];

    if (b < B) {
        const float* fp = feat + (size_t)b * 192;
        for (int i = lane; i < 192; i += 64) s_x[wid][i] = fp[i];
    }
    __syncthreads();

    if (b < B) {
        float ssum = 0.f, sdot = 0.f;
        #pragma unroll
        for (int t = 0; t < 16; ++t) {
            const int jk = t * 64 + lane;
            const int j = jk >> 5, k = jk & 31;
            float gg = 0.f;
            #pragma unroll
            for (int i = 0; i < 6; ++i)
                gg = fmaf(s_x[wid][i * 32 + j], s_x[wid][i * 32 + k], gg);
            ssum = fmaf(gg, gg, ssum);
            sdot = fmaf(gg, w_aff[jk], sdot);
        }
        #pragma unroll
        for (int off = 32; off >= 1; off >>= 1) {
            ssum += __shfl_xor(ssum, off, 64);
            sdot += __shfl_xor(sdot, off, 64);
        }
        if (lane == 0) out[b] = sdot / (sqrtf(ssum) + 1e-12f) + b_aff[0];
    }
}

extern "C" void kernel_launch(void* const* d_in, const int* in_sizes, int n_in,
                              void* d_out, int out_size, void* d_ws, size_t ws_size,
                              hipStream_t stream)
{
    const float* protein = (const float*)d_in[0];  // (B, 25, 1000)
    const float* ligand  = (const float*)d_in[1];  // (B, 64, 100)
    const float* w_pro   = (const float*)d_in[2];  // (96, 25, 8)
    const float* b_pro   = (const float*)d_in[3];  // (96,)
    const float* w_lig   = (const float*)d_in[4];  // (96, 64, 4)
    const float* b_lig   = (const float*)d_in[5];  // (96,)
    const float* w_aff   = (const float*)d_in[6];  // (1024,)
    const float* b_aff   = (const float*)d_in[7];  // (1,)
    float* out = (float*)d_out;
    const int B = out_size;                        // 4096

    float* feat   = (float*)d_ws;                              // (B,192) f32
    f16*   wpackP = (f16*)((char*)d_ws + (size_t)B * 192 * 4); // 24576 f16
    f16*   wpackL = wpackP + 24576;                            // 24576 f16

    repack_pro_kernel<<<96, 256, 0, stream>>>(w_pro, wpackP);
    repack_lig_kernel<<<96, 256, 0, stream>>>(w_lig, wpackL);

    // merged conv: blocks [0,B) protein -> feat[:,96:], [B,2B) ligand -> feat[:,:96]
    conv_kernel<<<2 * B, 512, 0, stream>>>(
        protein, wpackP, b_pro, ligand, wpackL, b_lig, feat, B);

    gram_affinity_kernel<<<(B + 3) / 4, 256, 0, stream>>>(feat, w_aff, b_aff, out, B);
}